// Round 1
// baseline (486.029 us; speedup 1.0000x reference)
//
#include <hip/hip_runtime.h>

#define BB 4
#define SS 32
#define HH 8
#define LL 128
#define DD 512
#define DI 2048
#define EPSN 1e-6f
#define INV_TEMP 0.04419417382415922f   // 1/sqrt(512)

// ---------------------------------------------------------------------------
// K1: attention logits + mask + softmax.  One block per (b,s,h), 128 threads
// (thread l owns row l).  attn written to d_out's second segment.
// ---------------------------------------------------------------------------
__global__ __launch_bounds__(LL) void attn_kernel(
    const float* __restrict__ x, const int* __restrict__ mask,
    const float* __restrict__ w, float* __restrict__ attn_out) {
  int bx = blockIdx.x;            // (b*S+s)*H + h
  int h  = bx % HH;
  int bs = bx / HH;               // b*S + s
  int l  = threadIdx.x;           // 0..127

  const float4* xr = (const float4*)(x + ((size_t)bs * LL + l) * DD);
  const float4* wr = (const float4*)(w + ((size_t)h  * LL + l) * DD);
  float acc = 0.f;
#pragma unroll 4
  for (int i = 0; i < DD / 4; ++i) {
    float4 a = xr[i];
    float4 b = wr[i];
    acc += a.x * b.x + a.y * b.y + a.z * b.z + a.w * b.w;
  }
  float logit = acc * INV_TEMP;
  if (mask[bs * LL + l] == 0) logit = -1e9f;

  __shared__ float red[LL];
  red[l] = logit;
  __syncthreads();
  for (int off = LL / 2; off > 0; off >>= 1) {
    if (l < off) red[l] = fmaxf(red[l], red[l + off]);
    __syncthreads();
  }
  float m = red[0];
  __syncthreads();
  float e = __expf(logit - m);
  red[l] = e;
  __syncthreads();
  for (int off = LL / 2; off > 0; off >>= 1) {
    if (l < off) red[l] += red[l + off];
    __syncthreads();
  }
  float inv = 1.f / red[0];
  attn_out[(size_t)bx * LL + l] = e * inv;
}

// ---------------------------------------------------------------------------
// K2+K3 fused: xa[h,e] = sum_l attn[h,l]*x[l,e]  (contraction reorder: H<L),
// then out[h,d] = sum_e v_w[d,e]*xa[h,e], then LayerNorm per (h) row.
// One block per (b,s), 256 threads.
// ---------------------------------------------------------------------------
__global__ __launch_bounds__(256) void mid_kernel(
    const float* __restrict__ x, const float* __restrict__ attn,
    const float* __restrict__ v_w, const float* __restrict__ ln_g,
    const float* __restrict__ ln_b, float* __restrict__ out_ln) {
  int bs = blockIdx.x;
  int t  = threadIdx.x;

  __shared__ float sattn[HH][LL];   // 4 KB
  __shared__ float sxa[HH][DD];     // 16 KB
  __shared__ float sout[HH][DD];    // 16 KB

  for (int i = t; i < HH * LL; i += 256)
    ((float*)sattn)[i] = attn[(size_t)bs * HH * LL + i];
  __syncthreads();

  // xa: thread t owns columns e0=t, e1=t+256 for all 8 heads
  float acc[HH][2];
#pragma unroll
  for (int h = 0; h < HH; ++h) { acc[h][0] = 0.f; acc[h][1] = 0.f; }
  const float* xb = x + (size_t)bs * LL * DD;
  for (int l = 0; l < LL; ++l) {
    float x0 = xb[l * DD + t];
    float x1 = xb[l * DD + t + 256];
#pragma unroll
    for (int h = 0; h < HH; ++h) {
      float a = sattn[h][l];
      acc[h][0] += a * x0;
      acc[h][1] += a * x1;
    }
  }
#pragma unroll
  for (int h = 0; h < HH; ++h) {
    sxa[h][t]       = acc[h][0];
    sxa[h][t + 256] = acc[h][1];
  }
  __syncthreads();

  // out[h][d] = sum_e v_w[d][e] * sxa[h][e]; thread owns d0=t, d1=t+256
  float vacc[HH][2];
#pragma unroll
  for (int h = 0; h < HH; ++h) { vacc[h][0] = 0.f; vacc[h][1] = 0.f; }
  const float4* vw0 = (const float4*)(v_w + (size_t)t * DD);
  const float4* vw1 = (const float4*)(v_w + (size_t)(t + 256) * DD);
  for (int e4 = 0; e4 < DD / 4; ++e4) {
    float4 w0 = vw0[e4];
    float4 w1 = vw1[e4];
    int e = e4 * 4;
#pragma unroll
    for (int h = 0; h < HH; ++h) {
      float s0 = sxa[h][e], s1 = sxa[h][e + 1], s2 = sxa[h][e + 2], s3 = sxa[h][e + 3];
      vacc[h][0] += w0.x * s0 + w0.y * s1 + w0.z * s2 + w0.w * s3;
      vacc[h][1] += w1.x * s0 + w1.y * s1 + w1.z * s2 + w1.w * s3;
    }
  }
#pragma unroll
  for (int h = 0; h < HH; ++h) {
    sout[h][t]       = vacc[h][0];
    sout[h][t + 256] = vacc[h][1];
  }
  __syncthreads();

  // LayerNorm per head row: 4 waves, each wave does rows wv and wv+4
  int wv = t >> 6, lane = t & 63;
  for (int r = wv; r < HH; r += 4) {
    float sum = 0.f, sq = 0.f;
    float vals[8];
#pragma unroll
    for (int k = 0; k < 8; ++k) {
      float v = sout[r][lane + 64 * k];
      vals[k] = v;
      sum += v;
      sq += v * v;
    }
#pragma unroll
    for (int off = 32; off > 0; off >>= 1) {
      sum += __shfl_xor(sum, off);
      sq  += __shfl_xor(sq, off);
    }
    float mu  = sum * (1.f / DD);
    float var = sq * (1.f / DD) - mu * mu;
    float rs  = rsqrtf(var + EPSN);
    float* op = out_ln + ((size_t)bs * HH + r) * DD;
#pragma unroll
    for (int k = 0; k < 8; ++k) {
      int d = lane + 64 * k;
      op[d] = (vals[k] - mu) * rs * ln_g[d] + ln_b[d];
    }
  }
}

// ---------------------------------------------------------------------------
// K4: FFN (relu(x@w1.T+b1)@w2.T + b2 + x) + LayerNorm.
// One block per 4 head-rows of a (b,s): grid = B*S*2, 256 threads.
// ---------------------------------------------------------------------------
__global__ __launch_bounds__(256) void ffn_kernel(
    const float* __restrict__ out_ln, const float* __restrict__ w1,
    const float* __restrict__ b1, const float* __restrict__ w2,
    const float* __restrict__ b2, const float* __restrict__ fln_g,
    const float* __restrict__ fln_b, float* __restrict__ y_out) {
  int bx = blockIdx.x;
  int bs = bx >> 1;
  int h0 = (bx & 1) * 4;
  int t  = threadIdx.x;

  __shared__ float sx[4][DD];    // 8 KB
  __shared__ float sh1[4][DI];   // 32 KB
  __shared__ float sy[4][DD];    // 8 KB

  const float* xb = out_ln + ((size_t)bs * HH + h0) * DD;
  for (int i = t; i < 4 * DD; i += 256) ((float*)sx)[i] = xb[i];
  __syncthreads();

  // h1[r][f] = relu(sum_d w1[f][d]*sx[r][d] + b1[f]); thread owns 8 f's
  for (int fi = 0; fi < DI / 256; ++fi) {
    int f = t + fi * 256;
    const float4* wr = (const float4*)(w1 + (size_t)f * DD);
    float a[4] = {0.f, 0.f, 0.f, 0.f};
    for (int d4 = 0; d4 < DD / 4; ++d4) {
      float4 wv = wr[d4];
      int d = d4 * 4;
#pragma unroll
      for (int r = 0; r < 4; ++r) {
        a[r] += wv.x * sx[r][d] + wv.y * sx[r][d + 1] +
                wv.z * sx[r][d + 2] + wv.w * sx[r][d + 3];
      }
    }
    float bb = b1[f];
#pragma unroll
    for (int r = 0; r < 4; ++r) sh1[r][f] = fmaxf(a[r] + bb, 0.f);
  }
  __syncthreads();

  // y[r][d] = sum_f w2[d][f]*h1[r][f] + b2[d] + sx[r][d]; thread owns 2 d's
  float ya[4][2];
#pragma unroll
  for (int di = 0; di < 2; ++di) {
    int d = t + di * 256;
    const float4* wr = (const float4*)(w2 + (size_t)d * DI);
    float a[4] = {0.f, 0.f, 0.f, 0.f};
    for (int f4 = 0; f4 < DI / 4; ++f4) {
      float4 wv = wr[f4];
      int f = f4 * 4;
#pragma unroll
      for (int r = 0; r < 4; ++r) {
        a[r] += wv.x * sh1[r][f] + wv.y * sh1[r][f + 1] +
                wv.z * sh1[r][f + 2] + wv.w * sh1[r][f + 3];
      }
    }
    float bb = b2[d];
#pragma unroll
    for (int r = 0; r < 4; ++r) ya[r][di] = a[r] + bb;
  }
  // residual, stage for LN
#pragma unroll
  for (int di = 0; di < 2; ++di) {
    int d = t + di * 256;
#pragma unroll
    for (int r = 0; r < 4; ++r) sy[r][d] = ya[r][di] + sx[r][d];
  }
  __syncthreads();

  // final LayerNorm: one wave per row (4 waves, 4 rows)
  int wv = t >> 6, lane = t & 63;
  int r = wv;
  float sum = 0.f, sq = 0.f;
  float vals[8];
#pragma unroll
  for (int k = 0; k < 8; ++k) {
    float v = sy[r][lane + 64 * k];
    vals[k] = v;
    sum += v;
    sq += v * v;
  }
#pragma unroll
  for (int off = 32; off > 0; off >>= 1) {
    sum += __shfl_xor(sum, off);
    sq  += __shfl_xor(sq, off);
  }
  float mu  = sum * (1.f / DD);
  float var = sq * (1.f / DD) - mu * mu;
  float rs  = rsqrtf(var + EPSN);
  float* yp = y_out + ((size_t)bs * HH + h0 + r) * DD;
#pragma unroll
  for (int k = 0; k < 8; ++k) {
    int d = lane + 64 * k;
    yp[d] = (vals[k] - mu) * rs * fln_g[d] + fln_b[d];
  }
}

extern "C" void kernel_launch(void* const* d_in, const int* in_sizes, int n_in,
                              void* d_out, int out_size, void* d_ws, size_t ws_size,
                              hipStream_t stream) {
  const float* x     = (const float*)d_in[0];
  const int*   mask  = (const int*)d_in[1];
  const float* w     = (const float*)d_in[2];
  const float* v_w   = (const float*)d_in[3];
  const float* ln_g  = (const float*)d_in[4];
  const float* ln_b  = (const float*)d_in[5];
  const float* w1    = (const float*)d_in[6];
  const float* b1    = (const float*)d_in[7];
  const float* w2    = (const float*)d_in[8];
  const float* b2    = (const float*)d_in[9];
  const float* fln_g = (const float*)d_in[10];
  const float* fln_b = (const float*)d_in[11];

  float* y    = (float*)d_out;
  float* attn = y + (size_t)BB * SS * HH * DD;  // second output segment
  float* o_ln = (float*)d_ws;                   // (B,S,H,D) = 2 MB scratch

  attn_kernel<<<BB * SS * HH, LL, 0, stream>>>(x, mask, w, attn);
  mid_kernel<<<BB * SS, 256, 0, stream>>>(x, attn, v_w, ln_g, ln_b, o_ln);
  ffn_kernel<<<BB * SS * 2, 256, 0, stream>>>(o_ln, w1, b1, w2, b2, fln_g, fln_b, y);
}

// Round 2
// 277.204 us; speedup vs baseline: 1.7533x; 1.7533x over previous
//
#include <hip/hip_runtime.h>
#include <hip/hip_bf16.h>

#define BB 4
#define SS 32
#define HH 8
#define LL 128
#define DD 512
#define DI 2048
#define EPSN 1e-6f
#define INV_TEMP 0.04419417382415922f   // 1/sqrt(512)

typedef __attribute__((ext_vector_type(8))) short short8;
typedef __attribute__((ext_vector_type(4))) float float4v;

static __device__ __forceinline__ unsigned short f2b(float f) {
  __hip_bfloat16 h = __float2bfloat16(f);
  return *(unsigned short*)&h;
}

// ---------------------------------------------------------------------------
// K0: cast w1,w2 fp32 -> bf16 (rounds to nearest even)
// ---------------------------------------------------------------------------
__global__ __launch_bounds__(256) void cast_w_kernel(
    const float* __restrict__ w1, const float* __restrict__ w2,
    unsigned short* __restrict__ w1b, unsigned short* __restrict__ w2b) {
  const int n1 = DI * DD;             // 1048576 elems each
  int idx = blockIdx.x * 256 + threadIdx.x;   // float4 granules
  int total4 = (2 * n1) / 4;
  for (int i = idx; i < total4; i += gridDim.x * 256) {
    const float4* src;
    unsigned short* dst;
    int j = i;
    if (i < n1 / 4) { src = (const float4*)w1; dst = w1b; }
    else            { src = (const float4*)w2; dst = w2b; j = i - n1 / 4; }
    float4 v = src[j];
    dst[j * 4 + 0] = f2b(v.x);
    dst[j * 4 + 1] = f2b(v.y);
    dst[j * 4 + 2] = f2b(v.z);
    dst[j * 4 + 3] = f2b(v.w);
  }
}

// ---------------------------------------------------------------------------
// K1: attention logits + mask + softmax (unchanged from r1)
// ---------------------------------------------------------------------------
__global__ __launch_bounds__(LL) void attn_kernel(
    const float* __restrict__ x, const int* __restrict__ mask,
    const float* __restrict__ w, float* __restrict__ attn_out) {
  int bx = blockIdx.x;
  int h  = bx % HH;
  int bs = bx / HH;
  int l  = threadIdx.x;

  const float4* xr = (const float4*)(x + ((size_t)bs * LL + l) * DD);
  const float4* wr = (const float4*)(w + ((size_t)h  * LL + l) * DD);
  float acc = 0.f;
#pragma unroll 4
  for (int i = 0; i < DD / 4; ++i) {
    float4 a = xr[i];
    float4 b = wr[i];
    acc += a.x * b.x + a.y * b.y + a.z * b.z + a.w * b.w;
  }
  float logit = acc * INV_TEMP;
  if (mask[bs * LL + l] == 0) logit = -1e9f;

  __shared__ float red[LL];
  red[l] = logit;
  __syncthreads();
  for (int off = LL / 2; off > 0; off >>= 1) {
    if (l < off) red[l] = fmaxf(red[l], red[l + off]);
    __syncthreads();
  }
  float m = red[0];
  __syncthreads();
  float e = __expf(logit - m);
  red[l] = e;
  __syncthreads();
  for (int off = LL / 2; off > 0; off >>= 1) {
    if (l < off) red[l] += red[l + off];
    __syncthreads();
  }
  float inv = 1.f / red[0];
  attn_out[(size_t)bx * LL + l] = e * inv;
}

// ---------------------------------------------------------------------------
// K2: xa = attn-weighted x, out = xa @ v_w^T, LayerNorm.
// Writes out_ln fp32 (residual) AND bf16 (GEMM A-matrix).
// ---------------------------------------------------------------------------
__global__ __launch_bounds__(256) void mid_kernel(
    const float* __restrict__ x, const float* __restrict__ attn,
    const float* __restrict__ v_w, const float* __restrict__ ln_g,
    const float* __restrict__ ln_b, float* __restrict__ out_ln,
    unsigned short* __restrict__ out_lnb) {
  int bs = blockIdx.x;
  int t  = threadIdx.x;

  __shared__ float sattn[HH][LL];
  __shared__ float sxa[HH][DD];
  __shared__ float sout[HH][DD];

  for (int i = t; i < HH * LL; i += 256)
    ((float*)sattn)[i] = attn[(size_t)bs * HH * LL + i];
  __syncthreads();

  float acc[HH][2];
#pragma unroll
  for (int h = 0; h < HH; ++h) { acc[h][0] = 0.f; acc[h][1] = 0.f; }
  const float* xb = x + (size_t)bs * LL * DD;
  for (int l = 0; l < LL; ++l) {
    float x0 = xb[l * DD + t];
    float x1 = xb[l * DD + t + 256];
#pragma unroll
    for (int h = 0; h < HH; ++h) {
      float a = sattn[h][l];
      acc[h][0] += a * x0;
      acc[h][1] += a * x1;
    }
  }
#pragma unroll
  for (int h = 0; h < HH; ++h) {
    sxa[h][t]       = acc[h][0];
    sxa[h][t + 256] = acc[h][1];
  }
  __syncthreads();

  float vacc[HH][2];
#pragma unroll
  for (int h = 0; h < HH; ++h) { vacc[h][0] = 0.f; vacc[h][1] = 0.f; }
  const float4* vw0 = (const float4*)(v_w + (size_t)t * DD);
  const float4* vw1 = (const float4*)(v_w + (size_t)(t + 256) * DD);
  for (int e4 = 0; e4 < DD / 4; ++e4) {
    float4 w0 = vw0[e4];
    float4 w1 = vw1[e4];
    int e = e4 * 4;
#pragma unroll
    for (int h = 0; h < HH; ++h) {
      float s0 = sxa[h][e], s1 = sxa[h][e + 1], s2 = sxa[h][e + 2], s3 = sxa[h][e + 3];
      vacc[h][0] += w0.x * s0 + w0.y * s1 + w0.z * s2 + w0.w * s3;
      vacc[h][1] += w1.x * s0 + w1.y * s1 + w1.z * s2 + w1.w * s3;
    }
  }
#pragma unroll
  for (int h = 0; h < HH; ++h) {
    sout[h][t]       = vacc[h][0];
    sout[h][t + 256] = vacc[h][1];
  }
  __syncthreads();

  int wv = t >> 6, lane = t & 63;
  for (int r = wv; r < HH; r += 4) {
    float sum = 0.f, sq = 0.f;
    float vals[8];
#pragma unroll
    for (int k = 0; k < 8; ++k) {
      float v = sout[r][lane + 64 * k];
      vals[k] = v;
      sum += v;
      sq += v * v;
    }
#pragma unroll
    for (int off = 32; off > 0; off >>= 1) {
      sum += __shfl_xor(sum, off);
      sq  += __shfl_xor(sq, off);
    }
    float mu  = sum * (1.f / DD);
    float var = sq * (1.f / DD) - mu * mu;
    float rs  = rsqrtf(var + EPSN);
    float* op = out_ln + ((size_t)bs * HH + r) * DD;
    unsigned short* opb = out_lnb + ((size_t)bs * HH + r) * DD;
#pragma unroll
    for (int k = 0; k < 8; ++k) {
      int d = lane + 64 * k;
      float v = (vals[k] - mu) * rs * ln_g[d] + ln_b[d];
      op[d]  = v;
      opb[d] = f2b(v);
    }
  }
}

// ---------------------------------------------------------------------------
// K3: GEMM1  h1 = relu(xln @ w1^T + b1), bf16 MFMA.
// M=1024 N=2048 K=512.  Block tile 128x64, 4 waves: each wave 32Mx64N
// (2 M-frags x 4 N-frags).  grid = 8*32 = 256 blocks.  No LDS.
// ---------------------------------------------------------------------------
__global__ __launch_bounds__(256) void gemm1_kernel(
    const unsigned short* __restrict__ xb, const unsigned short* __restrict__ w1b,
    const float* __restrict__ b1, unsigned short* __restrict__ h1b) {
  int blk = blockIdx.x;
  int nt = blk % 32, mt = blk / 32;
  int wv = threadIdx.x >> 6, lane = threadIdx.x & 63;
  int lm = lane & 15, lq = lane >> 4;

  int m0 = mt * 128 + wv * 32;
  int n0 = nt * 64;

  const short8* A0 = (const short8*)(xb + (size_t)(m0 + lm) * DD);
  const short8* A1 = (const short8*)(xb + (size_t)(m0 + 16 + lm) * DD);
  const short8* Bp[4];
#pragma unroll
  for (int nf = 0; nf < 4; ++nf)
    Bp[nf] = (const short8*)(w1b + (size_t)(n0 + nf * 16 + lm) * DD);

  float4v acc[2][4];
#pragma unroll
  for (int i = 0; i < 2; ++i)
#pragma unroll
    for (int nf = 0; nf < 4; ++nf) acc[i][nf] = (float4v){0.f, 0.f, 0.f, 0.f};

#pragma unroll 2
  for (int ks = 0; ks < DD / 32; ++ks) {
    short8 a0 = A0[ks * 4 + lq];
    short8 a1 = A1[ks * 4 + lq];
    short8 b[4];
#pragma unroll
    for (int nf = 0; nf < 4; ++nf) b[nf] = Bp[nf][ks * 4 + lq];
#pragma unroll
    for (int nf = 0; nf < 4; ++nf) {
      acc[0][nf] = __builtin_amdgcn_mfma_f32_16x16x32_bf16(a0, b[nf], acc[0][nf], 0, 0, 0);
      acc[1][nf] = __builtin_amdgcn_mfma_f32_16x16x32_bf16(a1, b[nf], acc[1][nf], 0, 0, 0);
    }
  }

#pragma unroll
  for (int i = 0; i < 2; ++i)
#pragma unroll
    for (int nf = 0; nf < 4; ++nf) {
      int col = n0 + nf * 16 + lm;
      float bb = b1[col];
#pragma unroll
      for (int r = 0; r < 4; ++r) {
        int row = m0 + i * 16 + lq * 4 + r;
        float v = acc[i][nf][r] + bb;
        h1b[(size_t)row * DI + col] = f2b(fmaxf(v, 0.f));
      }
    }
}

// ---------------------------------------------------------------------------
// K4: GEMM2  y_pre = h1 @ w2^T (raw accum, fp32 out).
// M=1024 N=512 K=2048.  Block tile 64x64, 4 waves: each wave 16Mx64N.
// grid = 16*8 = 128 blocks.
// ---------------------------------------------------------------------------
__global__ __launch_bounds__(256) void gemm2_kernel(
    const unsigned short* __restrict__ h1b, const unsigned short* __restrict__ w2b,
    float* __restrict__ y_pre) {
  int blk = blockIdx.x;
  int nt = blk % 8, mt = blk / 8;
  int wv = threadIdx.x >> 6, lane = threadIdx.x & 63;
  int lm = lane & 15, lq = lane >> 4;

  int m0 = mt * 64 + wv * 16;
  int n0 = nt * 64;

  const short8* A0 = (const short8*)(h1b + (size_t)(m0 + lm) * DI);
  const short8* Bp[4];
#pragma unroll
  for (int nf = 0; nf < 4; ++nf)
    Bp[nf] = (const short8*)(w2b + (size_t)(n0 + nf * 16 + lm) * DI);

  float4v acc[4];
#pragma unroll
  for (int nf = 0; nf < 4; ++nf) acc[nf] = (float4v){0.f, 0.f, 0.f, 0.f};

#pragma unroll 2
  for (int ks = 0; ks < DI / 32; ++ks) {
    short8 a0 = A0[ks * 4 + lq];
    short8 b[4];
#pragma unroll
    for (int nf = 0; nf < 4; ++nf) b[nf] = Bp[nf][ks * 4 + lq];
#pragma unroll
    for (int nf = 0; nf < 4; ++nf)
      acc[nf] = __builtin_amdgcn_mfma_f32_16x16x32_bf16(a0, b[nf], acc[nf], 0, 0, 0);
  }

#pragma unroll
  for (int nf = 0; nf < 4; ++nf) {
    int col = n0 + nf * 16 + lm;
#pragma unroll
    for (int r = 0; r < 4; ++r) {
      int row = m0 + lq * 4 + r;
      y_pre[(size_t)row * DD + col] = acc[nf][r];
    }
  }
}

// ---------------------------------------------------------------------------
// K5: final LN:  y = LN(y_pre + b2 + out_ln) * g + b.  4 rows/block.
// ---------------------------------------------------------------------------
__global__ __launch_bounds__(256) void ln_final_kernel(
    const float* __restrict__ y_pre, const float* __restrict__ out_ln,
    const float* __restrict__ b2, const float* __restrict__ fln_g,
    const float* __restrict__ fln_b, float* __restrict__ y_out) {
  int wv = threadIdx.x >> 6, lane = threadIdx.x & 63;
  int row = blockIdx.x * 4 + wv;

  const float* yp = y_pre + (size_t)row * DD;
  const float* ol = out_ln + (size_t)row * DD;
  float vals[8];
  float sum = 0.f, sq = 0.f;
#pragma unroll
  for (int k = 0; k < 8; ++k) {
    int d = lane + 64 * k;
    float v = yp[d] + b2[d] + ol[d];
    vals[k] = v;
    sum += v;
    sq += v * v;
  }
#pragma unroll
  for (int off = 32; off > 0; off >>= 1) {
    sum += __shfl_xor(sum, off);
    sq  += __shfl_xor(sq, off);
  }
  float mu  = sum * (1.f / DD);
  float var = sq * (1.f / DD) - mu * mu;
  float rs  = rsqrtf(var + EPSN);
  float* yo = y_out + (size_t)row * DD;
#pragma unroll
  for (int k = 0; k < 8; ++k) {
    int d = lane + 64 * k;
    yo[d] = (vals[k] - mu) * rs * fln_g[d] + fln_b[d];
  }
}

extern "C" void kernel_launch(void* const* d_in, const int* in_sizes, int n_in,
                              void* d_out, int out_size, void* d_ws, size_t ws_size,
                              hipStream_t stream) {
  const float* x     = (const float*)d_in[0];
  const int*   mask  = (const int*)d_in[1];
  const float* w     = (const float*)d_in[2];
  const float* v_w   = (const float*)d_in[3];
  const float* ln_g  = (const float*)d_in[4];
  const float* ln_b  = (const float*)d_in[5];
  const float* w1    = (const float*)d_in[6];
  const float* b1    = (const float*)d_in[7];
  const float* w2    = (const float*)d_in[8];
  const float* b2    = (const float*)d_in[9];
  const float* fln_g = (const float*)d_in[10];
  const float* fln_b = (const float*)d_in[11];

  float* y    = (float*)d_out;
  float* attn = y + (size_t)BB * SS * HH * DD;

  // workspace layout (bytes)
  char* ws = (char*)d_ws;
  float*          o_ln  = (float*)(ws);                       // 2 MB
  unsigned short* o_lnb = (unsigned short*)(ws + 2097152);    // 1 MB
  unsigned short* w1b   = (unsigned short*)(ws + 3145728);    // 2 MB
  unsigned short* w2b   = (unsigned short*)(ws + 5242880);    // 2 MB
  unsigned short* h1b   = (unsigned short*)(ws + 7340032);    // 4 MB
  float*          y_pre = (float*)(ws + 11534336);            // 2 MB

  cast_w_kernel<<<512, 256, 0, stream>>>(w1, w2, w1b, w2b);
  attn_kernel<<<BB * SS * HH, LL, 0, stream>>>(x, mask, w, attn);
  mid_kernel<<<BB * SS, 256, 0, stream>>>(x, attn, v_w, ln_g, ln_b, o_ln, o_lnb);
  gemm1_kernel<<<256, 256, 0, stream>>>(o_lnb, w1b, b1, h1b);
  gemm2_kernel<<<128, 256, 0, stream>>>(h1b, w2b, y_pre);
  ln_final_kernel<<<256, 256, 0, stream>>>(y_pre, o_ln, b2, fln_g, fln_b, y);
}

// Round 3
// 230.739 us; speedup vs baseline: 2.1064x; 1.2014x over previous
//
#include <hip/hip_runtime.h>
#include <hip/hip_bf16.h>

#define BB 4
#define SS 32
#define HH 8
#define LL 128
#define DD 512
#define DI 2048
#define EPSN 1e-6f
#define INV_TEMP 0.04419417382415922f   // 1/sqrt(512)

typedef __attribute__((ext_vector_type(8))) short short8;
typedef __attribute__((ext_vector_type(4))) float float4v;

static __device__ __forceinline__ unsigned short f2b(float f) {
  __hip_bfloat16 h = __float2bfloat16(f);
  return *(unsigned short*)&h;
}

// ---------------------------------------------------------------------------
// K0: cast w1, w2, v_w  fp32 -> bf16
// ---------------------------------------------------------------------------
__global__ __launch_bounds__(256) void cast_w_kernel(
    const float* __restrict__ w1, const float* __restrict__ w2,
    const float* __restrict__ v_w, unsigned short* __restrict__ w1b,
    unsigned short* __restrict__ w2b, unsigned short* __restrict__ v_wb) {
  const int n1 = (DI * DD) / 4;   // 262144 float4 granules in w1
  const int n2 = n1;              // w2
  const int n3 = (DD * DD) / 4;   // 65536 in v_w
  int i = blockIdx.x * 256 + threadIdx.x;
  if (i >= n1 + n2 + n3) return;
  const float4* src;
  unsigned short* dst;
  int j = i;
  if (i < n1)           { src = (const float4*)w1;  dst = w1b; }
  else if (i < n1 + n2) { src = (const float4*)w2;  dst = w2b; j = i - n1; }
  else                  { src = (const float4*)v_w; dst = v_wb; j = i - n1 - n2; }
  float4 v = src[j];
  dst[j * 4 + 0] = f2b(v.x);
  dst[j * 4 + 1] = f2b(v.y);
  dst[j * 4 + 2] = f2b(v.z);
  dst[j * 4 + 3] = f2b(v.w);
}

// ---------------------------------------------------------------------------
// K1: fused attention logits + softmax + attn-weighted readout (xa).
// One block per (b,s), 1024 threads (16 waves).
//   Phase A: wave per (h,l) pair, coalesced lane-wise dot + shuffle reduce.
//   Phase B: per-head softmax (8 waves), write attn output.
//   Phase C: xa[h,e] = sum_l attn[h,l]*x[l,e], coalesced, bf16 out.
// ---------------------------------------------------------------------------
__global__ __launch_bounds__(1024) void attn_xa_kernel(
    const float* __restrict__ x, const int* __restrict__ mask,
    const float* __restrict__ w, float* __restrict__ attn_out,
    unsigned short* __restrict__ xab) {
  int bs = blockIdx.x;
  int t  = threadIdx.x;
  int wv = t >> 6, lane = t & 63;

  __shared__ float slog[HH][LL];       // logits, then attn weights (4 KB)
  __shared__ float sxa2[2][HH][DD];    // partial xa (32 KB)

  const float* xb = x + (size_t)bs * LL * DD;

  // Phase A: 64 (h,l) pairs per wave
  for (int i = 0; i < 64; ++i) {
    int p = wv * 64 + i;
    int h = p >> 7, l = p & 127;
    const float4* xr = (const float4*)(xb + (size_t)l * DD) + lane * 2;
    const float4* wr = (const float4*)(w + ((size_t)h * LL + l) * DD) + lane * 2;
    float4 a0 = xr[0], a1 = xr[1];
    float4 b0 = wr[0], b1 = wr[1];
    float d = a0.x * b0.x + a0.y * b0.y + a0.z * b0.z + a0.w * b0.w +
              a1.x * b1.x + a1.y * b1.y + a1.z * b1.z + a1.w * b1.w;
#pragma unroll
    for (int off = 32; off > 0; off >>= 1) d += __shfl_xor(d, off);
    if (lane == 0) {
      float lg = d * INV_TEMP;
      if (mask[bs * LL + l] == 0) lg = -1e9f;
      slog[h][l] = lg;
    }
  }
  __syncthreads();

  // Phase B: softmax per head, waves 0..7
  if (wv < HH) {
    float v0 = slog[wv][lane], v1 = slog[wv][lane + 64];
    float m = fmaxf(v0, v1);
#pragma unroll
    for (int off = 32; off > 0; off >>= 1) m = fmaxf(m, __shfl_xor(m, off));
    float e0 = __expf(v0 - m), e1 = __expf(v1 - m);
    float s = e0 + e1;
#pragma unroll
    for (int off = 32; off > 0; off >>= 1) s += __shfl_xor(s, off);
    float inv = 1.f / s;
    e0 *= inv; e1 *= inv;
    slog[wv][lane] = e0;
    slog[wv][lane + 64] = e1;
    float* ao = attn_out + ((size_t)bs * HH + wv) * LL;
    ao[lane] = e0;
    ao[lane + 64] = e1;
  }
  __syncthreads();

  // Phase C: xa; thread owns column e for all 8 heads over half the l-range
  int e = t & (DD - 1), half = t >> 9;
  float acc[HH];
#pragma unroll
  for (int h = 0; h < HH; ++h) acc[h] = 0.f;
  int l0 = half * 64;
  for (int l = l0; l < l0 + 64; ++l) {
    float xv = xb[(size_t)l * DD + e];
#pragma unroll
    for (int h = 0; h < HH; ++h) acc[h] += slog[h][l] * xv;
  }
#pragma unroll
  for (int h = 0; h < HH; ++h) sxa2[half][h][e] = acc[h];
  __syncthreads();
  if (half == 0) {
    unsigned short* xo = xab + (size_t)bs * HH * DD;
#pragma unroll
    for (int h = 0; h < HH; ++h)
      xo[h * DD + e] = f2b(sxa2[0][h][e] + sxa2[1][h][e]);
  }
}

// ---------------------------------------------------------------------------
// K2: GEMM_V  out_pre = xa @ v_w^T.  M=1024 N=512 K=512 bf16 MFMA.
// Block tile 64x64, 4 waves (wave = 16Mx64N).  grid = 16*8 = 128.
// ---------------------------------------------------------------------------
__global__ __launch_bounds__(256) void gemm_v_kernel(
    const unsigned short* __restrict__ xab, const unsigned short* __restrict__ v_wb,
    float* __restrict__ out_pre) {
  int blk = blockIdx.x;
  int nt = blk % 8, mt = blk / 8;
  int wv = threadIdx.x >> 6, lane = threadIdx.x & 63;
  int lm = lane & 15, lq = lane >> 4;

  int m0 = mt * 64 + wv * 16;
  int n0 = nt * 64;

  const short8* A0 = (const short8*)(xab + (size_t)(m0 + lm) * DD);
  const short8* Bp[4];
#pragma unroll
  for (int nf = 0; nf < 4; ++nf)
    Bp[nf] = (const short8*)(v_wb + (size_t)(n0 + nf * 16 + lm) * DD);

  float4v acc[4];
#pragma unroll
  for (int nf = 0; nf < 4; ++nf) acc[nf] = (float4v){0.f, 0.f, 0.f, 0.f};

#pragma unroll 2
  for (int ks = 0; ks < DD / 32; ++ks) {
    short8 a0 = A0[ks * 4 + lq];
    short8 b[4];
#pragma unroll
    for (int nf = 0; nf < 4; ++nf) b[nf] = Bp[nf][ks * 4 + lq];
#pragma unroll
    for (int nf = 0; nf < 4; ++nf)
      acc[nf] = __builtin_amdgcn_mfma_f32_16x16x32_bf16(a0, b[nf], acc[nf], 0, 0, 0);
  }

#pragma unroll
  for (int nf = 0; nf < 4; ++nf) {
    int col = n0 + nf * 16 + lm;
#pragma unroll
    for (int r = 0; r < 4; ++r) {
      int row = m0 + lq * 4 + r;
      out_pre[(size_t)row * DD + col] = acc[nf][r];
    }
  }
}

// ---------------------------------------------------------------------------
// K3: mid LayerNorm: o_ln = LN(out_pre)*g+b, fp32 + bf16 copies.
// ---------------------------------------------------------------------------
__global__ __launch_bounds__(256) void ln_mid_kernel(
    const float* __restrict__ out_pre, const float* __restrict__ ln_g,
    const float* __restrict__ ln_b, float* __restrict__ o_ln,
    unsigned short* __restrict__ o_lnb) {
  int wv = threadIdx.x >> 6, lane = threadIdx.x & 63;
  int row = blockIdx.x * 4 + wv;

  const float* yp = out_pre + (size_t)row * DD;
  float vals[8];
  float sum = 0.f, sq = 0.f;
#pragma unroll
  for (int k = 0; k < 8; ++k) {
    float v = yp[lane + 64 * k];
    vals[k] = v;
    sum += v;
    sq += v * v;
  }
#pragma unroll
  for (int off = 32; off > 0; off >>= 1) {
    sum += __shfl_xor(sum, off);
    sq  += __shfl_xor(sq, off);
  }
  float mu  = sum * (1.f / DD);
  float var = sq * (1.f / DD) - mu * mu;
  float rs  = rsqrtf(var + EPSN);
  float* op = o_ln + (size_t)row * DD;
  unsigned short* opb = o_lnb + (size_t)row * DD;
#pragma unroll
  for (int k = 0; k < 8; ++k) {
    int d = lane + 64 * k;
    float v = (vals[k] - mu) * rs * ln_g[d] + ln_b[d];
    op[d]  = v;
    opb[d] = f2b(v);
  }
}

// ---------------------------------------------------------------------------
// K4: GEMM1  h1 = relu(xln @ w1^T + b1).  M=1024 N=2048 K=512.
// Block tile 128x64, 4 waves (wave = 32Mx64N).  grid = 256.
// ---------------------------------------------------------------------------
__global__ __launch_bounds__(256) void gemm1_kernel(
    const unsigned short* __restrict__ xb, const unsigned short* __restrict__ w1b,
    const float* __restrict__ b1, unsigned short* __restrict__ h1b) {
  int blk = blockIdx.x;
  int nt = blk % 32, mt = blk / 32;
  int wv = threadIdx.x >> 6, lane = threadIdx.x & 63;
  int lm = lane & 15, lq = lane >> 4;

  int m0 = mt * 128 + wv * 32;
  int n0 = nt * 64;

  const short8* A0 = (const short8*)(xb + (size_t)(m0 + lm) * DD);
  const short8* A1 = (const short8*)(xb + (size_t)(m0 + 16 + lm) * DD);
  const short8* Bp[4];
#pragma unroll
  for (int nf = 0; nf < 4; ++nf)
    Bp[nf] = (const short8*)(w1b + (size_t)(n0 + nf * 16 + lm) * DD);

  float4v acc[2][4];
#pragma unroll
  for (int i = 0; i < 2; ++i)
#pragma unroll
    for (int nf = 0; nf < 4; ++nf) acc[i][nf] = (float4v){0.f, 0.f, 0.f, 0.f};

#pragma unroll 2
  for (int ks = 0; ks < DD / 32; ++ks) {
    short8 a0 = A0[ks * 4 + lq];
    short8 a1 = A1[ks * 4 + lq];
    short8 b[4];
#pragma unroll
    for (int nf = 0; nf < 4; ++nf) b[nf] = Bp[nf][ks * 4 + lq];
#pragma unroll
    for (int nf = 0; nf < 4; ++nf) {
      acc[0][nf] = __builtin_amdgcn_mfma_f32_16x16x32_bf16(a0, b[nf], acc[0][nf], 0, 0, 0);
      acc[1][nf] = __builtin_amdgcn_mfma_f32_16x16x32_bf16(a1, b[nf], acc[1][nf], 0, 0, 0);
    }
  }

#pragma unroll
  for (int i = 0; i < 2; ++i)
#pragma unroll
    for (int nf = 0; nf < 4; ++nf) {
      int col = n0 + nf * 16 + lm;
      float bb = b1[col];
#pragma unroll
      for (int r = 0; r < 4; ++r) {
        int row = m0 + i * 16 + lq * 4 + r;
        float v = acc[i][nf][r] + bb;
        h1b[(size_t)row * DI + col] = f2b(fmaxf(v, 0.f));
      }
    }
}

// ---------------------------------------------------------------------------
// K5: GEMM2  y_pre = h1 @ w2^T.  M=1024 N=512 K=2048.
// Block tile 64x64, 4 waves.  grid = 128.
// ---------------------------------------------------------------------------
__global__ __launch_bounds__(256) void gemm2_kernel(
    const unsigned short* __restrict__ h1b, const unsigned short* __restrict__ w2b,
    float* __restrict__ y_pre) {
  int blk = blockIdx.x;
  int nt = blk % 8, mt = blk / 8;
  int wv = threadIdx.x >> 6, lane = threadIdx.x & 63;
  int lm = lane & 15, lq = lane >> 4;

  int m0 = mt * 64 + wv * 16;
  int n0 = nt * 64;

  const short8* A0 = (const short8*)(h1b + (size_t)(m0 + lm) * DI);
  const short8* Bp[4];
#pragma unroll
  for (int nf = 0; nf < 4; ++nf)
    Bp[nf] = (const short8*)(w2b + (size_t)(n0 + nf * 16 + lm) * DI);

  float4v acc[4];
#pragma unroll
  for (int nf = 0; nf < 4; ++nf) acc[nf] = (float4v){0.f, 0.f, 0.f, 0.f};

#pragma unroll 2
  for (int ks = 0; ks < DI / 32; ++ks) {
    short8 a0 = A0[ks * 4 + lq];
    short8 b[4];
#pragma unroll
    for (int nf = 0; nf < 4; ++nf) b[nf] = Bp[nf][ks * 4 + lq];
#pragma unroll
    for (int nf = 0; nf < 4; ++nf)
      acc[nf] = __builtin_amdgcn_mfma_f32_16x16x32_bf16(a0, b[nf], acc[nf], 0, 0, 0);
  }

#pragma unroll
  for (int nf = 0; nf < 4; ++nf) {
    int col = n0 + nf * 16 + lm;
#pragma unroll
    for (int r = 0; r < 4; ++r) {
      int row = m0 + lq * 4 + r;
      y_pre[(size_t)row * DD + col] = acc[nf][r];
    }
  }
}

// ---------------------------------------------------------------------------
// K6: final LN:  y = LN(y_pre + b2 + o_ln)*g + b.
// ---------------------------------------------------------------------------
__global__ __launch_bounds__(256) void ln_final_kernel(
    const float* __restrict__ y_pre, const float* __restrict__ o_ln,
    const float* __restrict__ b2, const float* __restrict__ fln_g,
    const float* __restrict__ fln_b, float* __restrict__ y_out) {
  int wv = threadIdx.x >> 6, lane = threadIdx.x & 63;
  int row = blockIdx.x * 4 + wv;

  const float* yp = y_pre + (size_t)row * DD;
  const float* ol = o_ln + (size_t)row * DD;
  float vals[8];
  float sum = 0.f, sq = 0.f;
#pragma unroll
  for (int k = 0; k < 8; ++k) {
    int d = lane + 64 * k;
    float v = yp[d] + b2[d] + ol[d];
    vals[k] = v;
    sum += v;
    sq += v * v;
  }
#pragma unroll
  for (int off = 32; off > 0; off >>= 1) {
    sum += __shfl_xor(sum, off);
    sq  += __shfl_xor(sq, off);
  }
  float mu  = sum * (1.f / DD);
  float var = sq * (1.f / DD) - mu * mu;
  float rs  = rsqrtf(var + EPSN);
  float* yo = y_out + (size_t)row * DD;
#pragma unroll
  for (int k = 0; k < 8; ++k) {
    int d = lane + 64 * k;
    yo[d] = (vals[k] - mu) * rs * fln_g[d] + fln_b[d];
  }
}

extern "C" void kernel_launch(void* const* d_in, const int* in_sizes, int n_in,
                              void* d_out, int out_size, void* d_ws, size_t ws_size,
                              hipStream_t stream) {
  const float* x     = (const float*)d_in[0];
  const int*   mask  = (const int*)d_in[1];
  const float* w     = (const float*)d_in[2];
  const float* v_w   = (const float*)d_in[3];
  const float* ln_g  = (const float*)d_in[4];
  const float* ln_b  = (const float*)d_in[5];
  const float* w1    = (const float*)d_in[6];
  const float* b1    = (const float*)d_in[7];
  const float* w2    = (const float*)d_in[8];
  const float* b2    = (const float*)d_in[9];
  const float* fln_g = (const float*)d_in[10];
  const float* fln_b = (const float*)d_in[11];

  float* y    = (float*)d_out;
  float* attn = y + (size_t)BB * SS * HH * DD;

  // workspace layout (bytes)
  char* ws = (char*)d_ws;
  float*          o_ln    = (float*)(ws);                       // 2 MB
  unsigned short* o_lnb   = (unsigned short*)(ws + 2097152);    // 1 MB
  unsigned short* w1b     = (unsigned short*)(ws + 3145728);    // 2 MB
  unsigned short* w2b     = (unsigned short*)(ws + 5242880);    // 2 MB
  unsigned short* h1b     = (unsigned short*)(ws + 7340032);    // 4 MB
  float*          y_pre   = (float*)(ws + 11534336);            // 2 MB
  unsigned short* v_wb    = (unsigned short*)(ws + 13631488);   // 512 KB
  unsigned short* xab     = (unsigned short*)(ws + 14155776);   // 1 MB
  float*          out_pre = (float*)(ws + 15204352);            // 2 MB

  const int cast_total = (DI * DD / 4) * 2 + (DD * DD / 4);
  cast_w_kernel<<<(cast_total + 255) / 256, 256, 0, stream>>>(w1, w2, v_w, w1b, w2b, v_wb);
  attn_xa_kernel<<<BB * SS, 1024, 0, stream>>>(x, mask, w, attn, xab);
  gemm_v_kernel<<<128, 256, 0, stream>>>(xab, v_wb, out_pre);
  ln_mid_kernel<<<256, 256, 0, stream>>>(out_pre, ln_g, ln_b, o_ln, o_lnb);
  gemm1_kernel<<<256, 256, 0, stream>>>(o_lnb, w1b, b1, h1b);
  gemm2_kernel<<<128, 256, 0, stream>>>(h1b, w2b, y_pre);
  ln_final_kernel<<<256, 256, 0, stream>>>(y_pre, o_ln, b2, fln_g, fln_b, y);
}

// Round 4
// 185.999 us; speedup vs baseline: 2.6131x; 1.2405x over previous
//
#include <hip/hip_runtime.h>
#include <hip/hip_bf16.h>

#define BB 4
#define SS 32
#define HH 8
#define LL 128
#define DD 512
#define DI 2048
#define EPSN 1e-6f
#define INV_TEMP 0.04419417382415922f   // 1/sqrt(512)

#define NLOGIT_BLK 4096                  // B*S*L / 4 waves
#define NCAST_GRAN ((DI*DD/4)*2 + (DD*DD/4))   // 589824 float4 granules
#define NCAST_BLK (NCAST_GRAN / 256)     // 2304

typedef __attribute__((ext_vector_type(8))) short short8;
typedef __attribute__((ext_vector_type(4))) float float4v;

static __device__ __forceinline__ unsigned short f2b(float f) {
  __hip_bfloat16 h = __float2bfloat16(f);
  return *(unsigned short*)&h;
}

// ---------------------------------------------------------------------------
// K1: fused [logits] + [weight cast].
//   blocks [0,4096): one wave per (bs,l); 8 head-dots, shuffle reduce.
//   blocks [4096,6400): fp32->bf16 cast of w1,w2,v_w.
// ---------------------------------------------------------------------------
__global__ __launch_bounds__(256) void pre_kernel(
    const float* __restrict__ x, const int* __restrict__ mask,
    const float* __restrict__ w, const float* __restrict__ w1,
    const float* __restrict__ w2, const float* __restrict__ v_w,
    unsigned short* __restrict__ w1b, unsigned short* __restrict__ w2b,
    unsigned short* __restrict__ v_wb, float* __restrict__ logits) {
  int blk = blockIdx.x;
  if (blk < NLOGIT_BLK) {
    int wv = threadIdx.x >> 6, lane = threadIdx.x & 63;
    int p  = blk * 4 + wv;           // (bs,l) pair index
    int bs = p >> 7, l = p & (LL - 1);

    const float4* xr = (const float4*)(x + ((size_t)bs * LL + l) * DD) + lane * 2;
    float4 x0 = xr[0], x1 = xr[1];

    float acc[HH];
#pragma unroll
    for (int h = 0; h < HH; ++h) {
      const float4* wr = (const float4*)(w + ((size_t)h * LL + l) * DD) + lane * 2;
      float4 w0 = wr[0], w1v = wr[1];
      acc[h] = x0.x * w0.x + x0.y * w0.y + x0.z * w0.z + x0.w * w0.w +
               x1.x * w1v.x + x1.y * w1v.y + x1.z * w1v.z + x1.w * w1v.w;
    }
#pragma unroll
    for (int off = 32; off > 0; off >>= 1) {
#pragma unroll
      for (int h = 0; h < HH; ++h) acc[h] += __shfl_xor(acc[h], off);
    }
    if (lane == 0) {
      int msk = mask[bs * LL + l];
#pragma unroll
      for (int h = 0; h < HH; ++h) {
        float lg = msk ? acc[h] * INV_TEMP : -1e9f;
        logits[((size_t)bs * HH + h) * LL + l] = lg;
      }
    }
  } else {
    const int n1 = (DI * DD) / 4;    // w1 granules
    const int n2 = n1;               // w2
    int i = (blk - NLOGIT_BLK) * 256 + threadIdx.x;
    const float4* src;
    unsigned short* dst;
    int j = i;
    if (i < n1)           { src = (const float4*)w1;  dst = w1b; }
    else if (i < n1 + n2) { src = (const float4*)w2;  dst = w2b;  j = i - n1; }
    else                  { src = (const float4*)v_w; dst = v_wb; j = i - n1 - n2; }
    float4 v = src[j];
    dst[j * 4 + 0] = f2b(v.x);
    dst[j * 4 + 1] = f2b(v.y);
    dst[j * 4 + 2] = f2b(v.z);
    dst[j * 4 + 3] = f2b(v.w);
  }
}

// ---------------------------------------------------------------------------
// K2: softmax (redundant per block-half, cheap) + xa contraction.
// One block per (bs, e-half): grid B*S*2 = 256, 256 threads.
// attn stored transposed in LDS -> contiguous 8-float reads per l.
// ---------------------------------------------------------------------------
__global__ __launch_bounds__(256) void xa_kernel(
    const float* __restrict__ x, const float* __restrict__ logits,
    float* __restrict__ attn_out, unsigned short* __restrict__ xab) {
  int bs = blockIdx.x >> 1, half = blockIdx.x & 1;
  int t = threadIdx.x, wv = t >> 6, lane = t & 63;

  __shared__ float sattn_t[LL][HH];   // transposed attn (4 KB)

  // softmax: wave wv handles heads wv and wv+4
  for (int h = wv; h < HH; h += 4) {
    const float* lg = logits + ((size_t)bs * HH + h) * LL;
    float v0 = lg[lane], v1 = lg[lane + 64];
    float m = fmaxf(v0, v1);
#pragma unroll
    for (int off = 32; off > 0; off >>= 1) m = fmaxf(m, __shfl_xor(m, off));
    float e0 = __expf(v0 - m), e1 = __expf(v1 - m);
    float s = e0 + e1;
#pragma unroll
    for (int off = 32; off > 0; off >>= 1) s += __shfl_xor(s, off);
    float inv = 1.f / s;
    e0 *= inv; e1 *= inv;
    sattn_t[lane][h]      = e0;
    sattn_t[lane + 64][h] = e1;
    if (half == 0) {
      float* ao = attn_out + ((size_t)bs * HH + h) * LL;
      ao[lane]      = e0;
      ao[lane + 64] = e1;
    }
  }
  __syncthreads();

  // xa[h][e] = sum_l attn[h][l] * x[l][e]; thread owns one e
  int e = half * 256 + t;
  const float* xb = x + (size_t)bs * LL * DD;
  float acc[HH];
#pragma unroll
  for (int h = 0; h < HH; ++h) acc[h] = 0.f;
  for (int l = 0; l < LL; ++l) {
    float xv = xb[(size_t)l * DD + e];
    float4 a0 = *(const float4*)&sattn_t[l][0];
    float4 a1 = *(const float4*)&sattn_t[l][4];
    acc[0] += a0.x * xv; acc[1] += a0.y * xv;
    acc[2] += a0.z * xv; acc[3] += a0.w * xv;
    acc[4] += a1.x * xv; acc[5] += a1.y * xv;
    acc[6] += a1.z * xv; acc[7] += a1.w * xv;
  }
  unsigned short* xo = xab + (size_t)bs * HH * DD;
#pragma unroll
  for (int h = 0; h < HH; ++h) xo[h * DD + e] = f2b(acc[h]);
}

// ---------------------------------------------------------------------------
// K3: GEMM_V  out_pre = xa @ v_w^T.  M=1024 N=512 K=512 bf16 MFMA.
// Block tile 64x64, 4 waves (wave = 16Mx64N).  grid = 128.
// ---------------------------------------------------------------------------
__global__ __launch_bounds__(256) void gemm_v_kernel(
    const unsigned short* __restrict__ xab, const unsigned short* __restrict__ v_wb,
    float* __restrict__ out_pre) {
  int blk = blockIdx.x;
  int nt = blk % 8, mt = blk / 8;
  int wv = threadIdx.x >> 6, lane = threadIdx.x & 63;
  int lm = lane & 15, lq = lane >> 4;

  int m0 = mt * 64 + wv * 16;
  int n0 = nt * 64;

  const short8* A0 = (const short8*)(xab + (size_t)(m0 + lm) * DD);
  const short8* Bp[4];
#pragma unroll
  for (int nf = 0; nf < 4; ++nf)
    Bp[nf] = (const short8*)(v_wb + (size_t)(n0 + nf * 16 + lm) * DD);

  float4v acc[4];
#pragma unroll
  for (int nf = 0; nf < 4; ++nf) acc[nf] = (float4v){0.f, 0.f, 0.f, 0.f};

#pragma unroll 2
  for (int ks = 0; ks < DD / 32; ++ks) {
    short8 a0 = A0[ks * 4 + lq];
    short8 b[4];
#pragma unroll
    for (int nf = 0; nf < 4; ++nf) b[nf] = Bp[nf][ks * 4 + lq];
#pragma unroll
    for (int nf = 0; nf < 4; ++nf)
      acc[nf] = __builtin_amdgcn_mfma_f32_16x16x32_bf16(a0, b[nf], acc[nf], 0, 0, 0);
  }

#pragma unroll
  for (int nf = 0; nf < 4; ++nf) {
    int col = n0 + nf * 16 + lm;
#pragma unroll
    for (int r = 0; r < 4; ++r) {
      int row = m0 + lq * 4 + r;
      out_pre[(size_t)row * DD + col] = acc[nf][r];
    }
  }
}

// ---------------------------------------------------------------------------
// K4: mid LayerNorm: o_ln = LN(out_pre)*g+b, fp32 + bf16 copies.
// ---------------------------------------------------------------------------
__global__ __launch_bounds__(256) void ln_mid_kernel(
    const float* __restrict__ out_pre, const float* __restrict__ ln_g,
    const float* __restrict__ ln_b, float* __restrict__ o_ln,
    unsigned short* __restrict__ o_lnb) {
  int wv = threadIdx.x >> 6, lane = threadIdx.x & 63;
  int row = blockIdx.x * 4 + wv;

  const float* yp = out_pre + (size_t)row * DD;
  float vals[8];
  float sum = 0.f, sq = 0.f;
#pragma unroll
  for (int k = 0; k < 8; ++k) {
    float v = yp[lane + 64 * k];
    vals[k] = v;
    sum += v;
    sq += v * v;
  }
#pragma unroll
  for (int off = 32; off > 0; off >>= 1) {
    sum += __shfl_xor(sum, off);
    sq  += __shfl_xor(sq, off);
  }
  float mu  = sum * (1.f / DD);
  float var = sq * (1.f / DD) - mu * mu;
  float rs  = rsqrtf(var + EPSN);
  float* op = o_ln + (size_t)row * DD;
  unsigned short* opb = o_lnb + (size_t)row * DD;
#pragma unroll
  for (int k = 0; k < 8; ++k) {
    int d = lane + 64 * k;
    float v = (vals[k] - mu) * rs * ln_g[d] + ln_b[d];
    op[d]  = v;
    opb[d] = f2b(v);
  }
}

// ---------------------------------------------------------------------------
// K5: GEMM1  h1 = relu(xln @ w1^T + b1).  M=1024 N=2048 K=512.
// Block tile 128x64, 4 waves (wave = 32Mx64N).  grid = 256.
// ---------------------------------------------------------------------------
__global__ __launch_bounds__(256) void gemm1_kernel(
    const unsigned short* __restrict__ xb, const unsigned short* __restrict__ w1b,
    const float* __restrict__ b1, unsigned short* __restrict__ h1b) {
  int blk = blockIdx.x;
  int nt = blk % 32, mt = blk / 32;
  int wv = threadIdx.x >> 6, lane = threadIdx.x & 63;
  int lm = lane & 15, lq = lane >> 4;

  int m0 = mt * 128 + wv * 32;
  int n0 = nt * 64;

  const short8* A0 = (const short8*)(xb + (size_t)(m0 + lm) * DD);
  const short8* A1 = (const short8*)(xb + (size_t)(m0 + 16 + lm) * DD);
  const short8* Bp[4];
#pragma unroll
  for (int nf = 0; nf < 4; ++nf)
    Bp[nf] = (const short8*)(w1b + (size_t)(n0 + nf * 16 + lm) * DD);

  float4v acc[2][4];
#pragma unroll
  for (int i = 0; i < 2; ++i)
#pragma unroll
    for (int nf = 0; nf < 4; ++nf) acc[i][nf] = (float4v){0.f, 0.f, 0.f, 0.f};

#pragma unroll 2
  for (int ks = 0; ks < DD / 32; ++ks) {
    short8 a0 = A0[ks * 4 + lq];
    short8 a1 = A1[ks * 4 + lq];
    short8 b[4];
#pragma unroll
    for (int nf = 0; nf < 4; ++nf) b[nf] = Bp[nf][ks * 4 + lq];
#pragma unroll
    for (int nf = 0; nf < 4; ++nf) {
      acc[0][nf] = __builtin_amdgcn_mfma_f32_16x16x32_bf16(a0, b[nf], acc[0][nf], 0, 0, 0);
      acc[1][nf] = __builtin_amdgcn_mfma_f32_16x16x32_bf16(a1, b[nf], acc[1][nf], 0, 0, 0);
    }
  }

#pragma unroll
  for (int i = 0; i < 2; ++i)
#pragma unroll
    for (int nf = 0; nf < 4; ++nf) {
      int col = n0 + nf * 16 + lm;
      float bb = b1[col];
#pragma unroll
      for (int r = 0; r < 4; ++r) {
        int row = m0 + i * 16 + lq * 4 + r;
        float v = acc[i][nf][r] + bb;
        h1b[(size_t)row * DI + col] = f2b(fmaxf(v, 0.f));
      }
    }
}

// ---------------------------------------------------------------------------
// K6: GEMM2  y_pre = h1 @ w2^T.  M=1024 N=512 K=2048.
// Block tile 64x64, 4 waves.  grid = 128.
// ---------------------------------------------------------------------------
__global__ __launch_bounds__(256) void gemm2_kernel(
    const unsigned short* __restrict__ h1b, const unsigned short* __restrict__ w2b,
    float* __restrict__ y_pre) {
  int blk = blockIdx.x;
  int nt = blk % 8, mt = blk / 8;
  int wv = threadIdx.x >> 6, lane = threadIdx.x & 63;
  int lm = lane & 15, lq = lane >> 4;

  int m0 = mt * 64 + wv * 16;
  int n0 = nt * 64;

  const short8* A0 = (const short8*)(h1b + (size_t)(m0 + lm) * DI);
  const short8* Bp[4];
#pragma unroll
  for (int nf = 0; nf < 4; ++nf)
    Bp[nf] = (const short8*)(w2b + (size_t)(n0 + nf * 16 + lm) * DI);

  float4v acc[4];
#pragma unroll
  for (int nf = 0; nf < 4; ++nf) acc[nf] = (float4v){0.f, 0.f, 0.f, 0.f};

#pragma unroll 2
  for (int ks = 0; ks < DI / 32; ++ks) {
    short8 a0 = A0[ks * 4 + lq];
    short8 b[4];
#pragma unroll
    for (int nf = 0; nf < 4; ++nf) b[nf] = Bp[nf][ks * 4 + lq];
#pragma unroll
    for (int nf = 0; nf < 4; ++nf)
      acc[nf] = __builtin_amdgcn_mfma_f32_16x16x32_bf16(a0, b[nf], acc[nf], 0, 0, 0);
  }

#pragma unroll
  for (int nf = 0; nf < 4; ++nf) {
    int col = n0 + nf * 16 + lm;
#pragma unroll
    for (int r = 0; r < 4; ++r) {
      int row = m0 + lq * 4 + r;
      y_pre[(size_t)row * DD + col] = acc[nf][r];
    }
  }
}

// ---------------------------------------------------------------------------
// K7: final LN:  y = LN(y_pre + b2 + o_ln)*g + b.
// ---------------------------------------------------------------------------
__global__ __launch_bounds__(256) void ln_final_kernel(
    const float* __restrict__ y_pre, const float* __restrict__ o_ln,
    const float* __restrict__ b2, const float* __restrict__ fln_g,
    const float* __restrict__ fln_b, float* __restrict__ y_out) {
  int wv = threadIdx.x >> 6, lane = threadIdx.x & 63;
  int row = blockIdx.x * 4 + wv;

  const float* yp = y_pre + (size_t)row * DD;
  const float* ol = o_ln + (size_t)row * DD;
  float vals[8];
  float sum = 0.f, sq = 0.f;
#pragma unroll
  for (int k = 0; k < 8; ++k) {
    int d = lane + 64 * k;
    float v = yp[d] + b2[d] + ol[d];
    vals[k] = v;
    sum += v;
    sq += v * v;
  }
#pragma unroll
  for (int off = 32; off > 0; off >>= 1) {
    sum += __shfl_xor(sum, off);
    sq  += __shfl_xor(sq, off);
  }
  float mu  = sum * (1.f / DD);
  float var = sq * (1.f / DD) - mu * mu;
  float rs  = rsqrtf(var + EPSN);
  float* yo = y_out + (size_t)row * DD;
#pragma unroll
  for (int k = 0; k < 8; ++k) {
    int d = lane + 64 * k;
    yo[d] = (vals[k] - mu) * rs * fln_g[d] + fln_b[d];
  }
}

extern "C" void kernel_launch(void* const* d_in, const int* in_sizes, int n_in,
                              void* d_out, int out_size, void* d_ws, size_t ws_size,
                              hipStream_t stream) {
  const float* x     = (const float*)d_in[0];
  const int*   mask  = (const int*)d_in[1];
  const float* w     = (const float*)d_in[2];
  const float* v_w   = (const float*)d_in[3];
  const float* ln_g  = (const float*)d_in[4];
  const float* ln_b  = (const float*)d_in[5];
  const float* w1    = (const float*)d_in[6];
  const float* b1    = (const float*)d_in[7];
  const float* w2    = (const float*)d_in[8];
  const float* b2    = (const float*)d_in[9];
  const float* fln_g = (const float*)d_in[10];
  const float* fln_b = (const float*)d_in[11];

  float* y    = (float*)d_out;
  float* attn = y + (size_t)BB * SS * HH * DD;

  // workspace layout (bytes)
  char* ws = (char*)d_ws;
  float*          o_ln    = (float*)(ws);                       // 2 MB
  unsigned short* o_lnb   = (unsigned short*)(ws + 2097152);    // 1 MB
  unsigned short* w1b     = (unsigned short*)(ws + 3145728);    // 2 MB
  unsigned short* w2b     = (unsigned short*)(ws + 5242880);    // 2 MB
  unsigned short* h1b     = (unsigned short*)(ws + 7340032);    // 4 MB
  float*          y_pre   = (float*)(ws + 11534336);            // 2 MB
  unsigned short* v_wb    = (unsigned short*)(ws + 13631488);   // 512 KB
  unsigned short* xab     = (unsigned short*)(ws + 14155776);   // 1 MB
  float*          out_pre = (float*)(ws + 15204352);            // 2 MB
  float*          logits  = (float*)(ws + 17301504);            // 512 KB

  pre_kernel<<<NLOGIT_BLK + NCAST_BLK, 256, 0, stream>>>(
      x, mask, w, w1, w2, v_w, w1b, w2b, v_wb, logits);
  xa_kernel<<<BB * SS * 2, 256, 0, stream>>>(x, logits, attn, xab);
  gemm_v_kernel<<<128, 256, 0, stream>>>(xab, v_wb, out_pre);
  ln_mid_kernel<<<256, 256, 0, stream>>>(out_pre, ln_g, ln_b, o_ln, o_lnb);
  gemm1_kernel<<<256, 256, 0, stream>>>(o_lnb, w1b, b1, h1b);
  gemm2_kernel<<<128, 256, 0, stream>>>(h1b, w2b, y_pre);
  ln_final_kernel<<<256, 256, 0, stream>>>(y_pre, o_ln, b2, fln_g, fln_b, y);
}

// Round 5
// 172.649 us; speedup vs baseline: 2.8151x; 1.0773x over previous
//
#include <hip/hip_runtime.h>
#include <hip/hip_bf16.h>

#define BB 4
#define SS 32
#define HH 8
#define LL 128
#define DD 512
#define DI 2048
#define EPSN 1e-6f
#define INV_TEMP 0.04419417382415922f   // 1/sqrt(512)

#define NLOGIT_BLK 4096                  // B*S*L / 4 waves
#define NCAST_GRAN ((DI*DD/4)*2 + (DD*DD/4))   // 589824 float4 granules
#define NCAST_BLK (NCAST_GRAN / 256)     // 2304

#define NROW (BB*SS*HH)                  // 1024 rows
#define SLICE ((size_t)NROW * DD)        // 524288 floats per K-split partial

typedef __attribute__((ext_vector_type(8))) short short8;
typedef __attribute__((ext_vector_type(4))) float float4v;

static __device__ __forceinline__ unsigned short f2b(float f) {
  __hip_bfloat16 h = __float2bfloat16(f);
  return *(unsigned short*)&h;
}

// ---------------------------------------------------------------------------
// K1: fused [logits] + [weight cast].
//   blocks [0,4096): one wave per (bs,l); 8 head-dots, shuffle reduce.
//   blocks [4096,6400): fp32->bf16 cast of w1,w2,v_w.
// ---------------------------------------------------------------------------
__global__ __launch_bounds__(256) void pre_kernel(
    const float* __restrict__ x, const int* __restrict__ mask,
    const float* __restrict__ w, const float* __restrict__ w1,
    const float* __restrict__ w2, const float* __restrict__ v_w,
    unsigned short* __restrict__ w1b, unsigned short* __restrict__ w2b,
    unsigned short* __restrict__ v_wb, float* __restrict__ logits) {
  int blk = blockIdx.x;
  if (blk < NLOGIT_BLK) {
    int wv = threadIdx.x >> 6, lane = threadIdx.x & 63;
    int p  = blk * 4 + wv;           // (bs,l) pair index
    int bs = p >> 7, l = p & (LL - 1);

    const float4* xr = (const float4*)(x + ((size_t)bs * LL + l) * DD) + lane * 2;
    float4 x0 = xr[0], x1 = xr[1];

    float acc[HH];
#pragma unroll
    for (int h = 0; h < HH; ++h) {
      const float4* wr = (const float4*)(w + ((size_t)h * LL + l) * DD) + lane * 2;
      float4 w0 = wr[0], w1v = wr[1];
      acc[h] = x0.x * w0.x + x0.y * w0.y + x0.z * w0.z + x0.w * w0.w +
               x1.x * w1v.x + x1.y * w1v.y + x1.z * w1v.z + x1.w * w1v.w;
    }
#pragma unroll
    for (int off = 32; off > 0; off >>= 1) {
#pragma unroll
      for (int h = 0; h < HH; ++h) acc[h] += __shfl_xor(acc[h], off);
    }
    if (lane == 0) {
      int msk = mask[bs * LL + l];
#pragma unroll
      for (int h = 0; h < HH; ++h) {
        float lg = msk ? acc[h] * INV_TEMP : -1e9f;
        logits[((size_t)bs * HH + h) * LL + l] = lg;
      }
    }
  } else {
    const int n1 = (DI * DD) / 4;    // w1 granules
    const int n2 = n1;               // w2
    int i = (blk - NLOGIT_BLK) * 256 + threadIdx.x;
    const float4* src;
    unsigned short* dst;
    int j = i;
    if (i < n1)           { src = (const float4*)w1;  dst = w1b; }
    else if (i < n1 + n2) { src = (const float4*)w2;  dst = w2b;  j = i - n1; }
    else                  { src = (const float4*)v_w; dst = v_wb; j = i - n1 - n2; }
    float4 v = src[j];
    dst[j * 4 + 0] = f2b(v.x);
    dst[j * 4 + 1] = f2b(v.y);
    dst[j * 4 + 2] = f2b(v.z);
    dst[j * 4 + 3] = f2b(v.w);
  }
}

// ---------------------------------------------------------------------------
// K2: softmax (redundant per block, cheap) + xa contraction, l-split x2.
// One block per (bs, e-half): grid B*S*2 = 256, 512 threads (8 waves).
// ---------------------------------------------------------------------------
__global__ __launch_bounds__(512) void xa_kernel(
    const float* __restrict__ x, const float* __restrict__ logits,
    float* __restrict__ attn_out, unsigned short* __restrict__ xab) {
  int bs = blockIdx.x >> 1, half = blockIdx.x & 1;
  int t = threadIdx.x, wv = t >> 6, lane = t & 63;

  __shared__ float sattn_t[LL][HH];      // transposed attn (4 KB)
  __shared__ float sxa[2][HH][256];      // partial xa (16 KB)

  // softmax: waves 0..3, wave wv handles heads wv and wv+4
  if (wv < 4) {
    for (int h = wv; h < HH; h += 4) {
      const float* lg = logits + ((size_t)bs * HH + h) * LL;
      float v0 = lg[lane], v1 = lg[lane + 64];
      float m = fmaxf(v0, v1);
#pragma unroll
      for (int off = 32; off > 0; off >>= 1) m = fmaxf(m, __shfl_xor(m, off));
      float e0 = __expf(v0 - m), e1 = __expf(v1 - m);
      float s = e0 + e1;
#pragma unroll
      for (int off = 32; off > 0; off >>= 1) s += __shfl_xor(s, off);
      float inv = 1.f / s;
      e0 *= inv; e1 *= inv;
      sattn_t[lane][h]      = e0;
      sattn_t[lane + 64][h] = e1;
      if (half == 0) {
        float* ao = attn_out + ((size_t)bs * HH + h) * LL;
        ao[lane]      = e0;
        ao[lane + 64] = e1;
      }
    }
  }
  __syncthreads();

  // xa[h][e] = sum_l attn[h][l]*x[l][e]; thread owns col, half the l-range
  int col = t & 255, lseg = t >> 8;
  int e = half * 256 + col;
  const float* xb = x + (size_t)bs * LL * DD;
  float acc[HH];
#pragma unroll
  for (int h = 0; h < HH; ++h) acc[h] = 0.f;
  int l0 = lseg * 64;
  for (int l = l0; l < l0 + 64; ++l) {
    float xv = xb[(size_t)l * DD + e];
    float4 a0 = *(const float4*)&sattn_t[l][0];
    float4 a1 = *(const float4*)&sattn_t[l][4];
    acc[0] += a0.x * xv; acc[1] += a0.y * xv;
    acc[2] += a0.z * xv; acc[3] += a0.w * xv;
    acc[4] += a1.x * xv; acc[5] += a1.y * xv;
    acc[6] += a1.z * xv; acc[7] += a1.w * xv;
  }
#pragma unroll
  for (int h = 0; h < HH; ++h) sxa[lseg][h][col] = acc[h];
  __syncthreads();
  if (t < 256) {
    unsigned short* xo = xab + (size_t)bs * HH * DD;
#pragma unroll
    for (int h = 0; h < HH; ++h)
      xo[h * DD + t + half * 256] = f2b(sxa[0][h][t] + sxa[1][h][t]);
  }
}

// ---------------------------------------------------------------------------
// K3: GEMM_V  vpart[ks] = xa @ v_w^T (K-chunk ks).  M=1024 N=512 K=512.
// Block 64x64, 4 waves (16Mx64N), K-split x4 (chunk=128).  grid=512.
// ---------------------------------------------------------------------------
__global__ __launch_bounds__(256) void gemm_v_kernel(
    const unsigned short* __restrict__ xab, const unsigned short* __restrict__ v_wb,
    float* __restrict__ vpart) {
  int blk = blockIdx.x;
  int nt = blk & 7, mt = (blk >> 3) & 15, kslice = blk >> 7;
  int wv = threadIdx.x >> 6, lane = threadIdx.x & 63;
  int lm = lane & 15, lq = lane >> 4;

  int m0 = mt * 64 + wv * 16;
  int n0 = nt * 64;
  int g0 = kslice * 16;   // short8 granule offset (128 elems)

  const short8* A0 = (const short8*)(xab + (size_t)(m0 + lm) * DD) + g0;
  const short8* Bp[4];
#pragma unroll
  for (int nf = 0; nf < 4; ++nf)
    Bp[nf] = (const short8*)(v_wb + (size_t)(n0 + nf * 16 + lm) * DD) + g0;

  float4v acc[4];
#pragma unroll
  for (int nf = 0; nf < 4; ++nf) acc[nf] = (float4v){0.f, 0.f, 0.f, 0.f};

#pragma unroll
  for (int ks = 0; ks < 4; ++ks) {
    short8 a0 = A0[ks * 4 + lq];
    short8 b[4];
#pragma unroll
    for (int nf = 0; nf < 4; ++nf) b[nf] = Bp[nf][ks * 4 + lq];
#pragma unroll
    for (int nf = 0; nf < 4; ++nf)
      acc[nf] = __builtin_amdgcn_mfma_f32_16x16x32_bf16(a0, b[nf], acc[nf], 0, 0, 0);
  }

  float* outp = vpart + (size_t)kslice * SLICE;
#pragma unroll
  for (int nf = 0; nf < 4; ++nf) {
    int col = n0 + nf * 16 + lm;
#pragma unroll
    for (int r = 0; r < 4; ++r) {
      int row = m0 + lq * 4 + r;
      outp[(size_t)row * DD + col] = acc[nf][r];
    }
  }
}

// ---------------------------------------------------------------------------
// K4: mid LayerNorm over sum of 4 partials: o_ln = LN(sum vpart)*g+b.
// ---------------------------------------------------------------------------
__global__ __launch_bounds__(256) void ln_mid_kernel(
    const float* __restrict__ vpart, const float* __restrict__ ln_g,
    const float* __restrict__ ln_b, float* __restrict__ o_ln,
    unsigned short* __restrict__ o_lnb) {
  int wv = threadIdx.x >> 6, lane = threadIdx.x & 63;
  int row = blockIdx.x * 4 + wv;

  const float* p0 = vpart + (size_t)row * DD;
  float vals[8];
  float sum = 0.f, sq = 0.f;
#pragma unroll
  for (int k = 0; k < 8; ++k) {
    int d = lane + 64 * k;
    float v = p0[d] + p0[SLICE + d] + p0[2 * SLICE + d] + p0[3 * SLICE + d];
    vals[k] = v;
    sum += v;
    sq += v * v;
  }
#pragma unroll
  for (int off = 32; off > 0; off >>= 1) {
    sum += __shfl_xor(sum, off);
    sq  += __shfl_xor(sq, off);
  }
  float mu  = sum * (1.f / DD);
  float var = sq * (1.f / DD) - mu * mu;
  float rs  = rsqrtf(var + EPSN);
  float* op = o_ln + (size_t)row * DD;
  unsigned short* opb = o_lnb + (size_t)row * DD;
#pragma unroll
  for (int k = 0; k < 8; ++k) {
    int d = lane + 64 * k;
    float v = (vals[k] - mu) * rs * ln_g[d] + ln_b[d];
    op[d]  = v;
    opb[d] = f2b(v);
  }
}

// ---------------------------------------------------------------------------
// K5: GEMM1  h1 = relu(xln @ w1^T + b1).  M=1024 N=2048 K=512.
// Block 64x64, 4 waves (16Mx64N).  grid = 16*32 = 512.
// ---------------------------------------------------------------------------
__global__ __launch_bounds__(256) void gemm1_kernel(
    const unsigned short* __restrict__ xb, const unsigned short* __restrict__ w1b,
    const float* __restrict__ b1, unsigned short* __restrict__ h1b) {
  int blk = blockIdx.x;
  int nt = blk & 31, mt = blk >> 5;
  int wv = threadIdx.x >> 6, lane = threadIdx.x & 63;
  int lm = lane & 15, lq = lane >> 4;

  int m0 = mt * 64 + wv * 16;
  int n0 = nt * 64;

  const short8* A0 = (const short8*)(xb + (size_t)(m0 + lm) * DD);
  const short8* Bp[4];
#pragma unroll
  for (int nf = 0; nf < 4; ++nf)
    Bp[nf] = (const short8*)(w1b + (size_t)(n0 + nf * 16 + lm) * DD);

  float4v acc[4];
#pragma unroll
  for (int nf = 0; nf < 4; ++nf) acc[nf] = (float4v){0.f, 0.f, 0.f, 0.f};

#pragma unroll 4
  for (int ks = 0; ks < DD / 32; ++ks) {
    short8 a0 = A0[ks * 4 + lq];
    short8 b[4];
#pragma unroll
    for (int nf = 0; nf < 4; ++nf) b[nf] = Bp[nf][ks * 4 + lq];
#pragma unroll
    for (int nf = 0; nf < 4; ++nf)
      acc[nf] = __builtin_amdgcn_mfma_f32_16x16x32_bf16(a0, b[nf], acc[nf], 0, 0, 0);
  }

#pragma unroll
  for (int nf = 0; nf < 4; ++nf) {
    int col = n0 + nf * 16 + lm;
    float bb = b1[col];
#pragma unroll
    for (int r = 0; r < 4; ++r) {
      int row = m0 + lq * 4 + r;
      float v = acc[nf][r] + bb;
      h1b[(size_t)row * DI + col] = f2b(fmaxf(v, 0.f));
    }
  }
}

// ---------------------------------------------------------------------------
// K6: GEMM2  ypart[ks] = h1 @ w2^T (K-chunk ks).  M=1024 N=512 K=2048.
// Block 64x64, 4 waves, K-split x4 (chunk=512).  grid=512.
// ---------------------------------------------------------------------------
__global__ __launch_bounds__(256) void gemm2_kernel(
    const unsigned short* __restrict__ h1b, const unsigned short* __restrict__ w2b,
    float* __restrict__ ypart) {
  int blk = blockIdx.x;
  int nt = blk & 7, mt = (blk >> 3) & 15, kslice = blk >> 7;
  int wv = threadIdx.x >> 6, lane = threadIdx.x & 63;
  int lm = lane & 15, lq = lane >> 4;

  int m0 = mt * 64 + wv * 16;
  int n0 = nt * 64;
  int g0 = kslice * 64;   // short8 granule offset (512 elems)

  const short8* A0 = (const short8*)(h1b + (size_t)(m0 + lm) * DI) + g0;
  const short8* Bp[4];
#pragma unroll
  for (int nf = 0; nf < 4; ++nf)
    Bp[nf] = (const short8*)(w2b + (size_t)(n0 + nf * 16 + lm) * DI) + g0;

  float4v acc[4];
#pragma unroll
  for (int nf = 0; nf < 4; ++nf) acc[nf] = (float4v){0.f, 0.f, 0.f, 0.f};

#pragma unroll 4
  for (int ks = 0; ks < 16; ++ks) {
    short8 a0 = A0[ks * 4 + lq];
    short8 b[4];
#pragma unroll
    for (int nf = 0; nf < 4; ++nf) b[nf] = Bp[nf][ks * 4 + lq];
#pragma unroll
    for (int nf = 0; nf < 4; ++nf)
      acc[nf] = __builtin_amdgcn_mfma_f32_16x16x32_bf16(a0, b[nf], acc[nf], 0, 0, 0);
  }

  float* outp = ypart + (size_t)kslice * SLICE;
#pragma unroll
  for (int nf = 0; nf < 4; ++nf) {
    int col = n0 + nf * 16 + lm;
#pragma unroll
    for (int r = 0; r < 4; ++r) {
      int row = m0 + lq * 4 + r;
      outp[(size_t)row * DD + col] = acc[nf][r];
    }
  }
}

// ---------------------------------------------------------------------------
// K7: final LN:  y = LN(sum ypart + b2 + o_ln)*g + b.
// ---------------------------------------------------------------------------
__global__ __launch_bounds__(256) void ln_final_kernel(
    const float* __restrict__ ypart, const float* __restrict__ o_ln,
    const float* __restrict__ b2, const float* __restrict__ fln_g,
    const float* __restrict__ fln_b, float* __restrict__ y_out) {
  int wv = threadIdx.x >> 6, lane = threadIdx.x & 63;
  int row = blockIdx.x * 4 + wv;

  const float* p0 = ypart + (size_t)row * DD;
  const float* ol = o_ln + (size_t)row * DD;
  float vals[8];
  float sum = 0.f, sq = 0.f;
#pragma unroll
  for (int k = 0; k < 8; ++k) {
    int d = lane + 64 * k;
    float v = p0[d] + p0[SLICE + d] + p0[2 * SLICE + d] + p0[3 * SLICE + d] +
              b2[d] + ol[d];
    vals[k] = v;
    sum += v;
    sq += v * v;
  }
#pragma unroll
  for (int off = 32; off > 0; off >>= 1) {
    sum += __shfl_xor(sum, off);
    sq  += __shfl_xor(sq, off);
  }
  float mu  = sum * (1.f / DD);
  float var = sq * (1.f / DD) - mu * mu;
  float rs  = rsqrtf(var + EPSN);
  float* yo = y_out + (size_t)row * DD;
#pragma unroll
  for (int k = 0; k < 8; ++k) {
    int d = lane + 64 * k;
    yo[d] = (vals[k] - mu) * rs * fln_g[d] + fln_b[d];
  }
}

extern "C" void kernel_launch(void* const* d_in, const int* in_sizes, int n_in,
                              void* d_out, int out_size, void* d_ws, size_t ws_size,
                              hipStream_t stream) {
  const float* x     = (const float*)d_in[0];
  const int*   mask  = (const int*)d_in[1];
  const float* w     = (const float*)d_in[2];
  const float* v_w   = (const float*)d_in[3];
  const float* ln_g  = (const float*)d_in[4];
  const float* ln_b  = (const float*)d_in[5];
  const float* w1    = (const float*)d_in[6];
  const float* b1    = (const float*)d_in[7];
  const float* w2    = (const float*)d_in[8];
  const float* b2    = (const float*)d_in[9];
  const float* fln_g = (const float*)d_in[10];
  const float* fln_b = (const float*)d_in[11];

  float* y    = (float*)d_out;
  float* attn = y + (size_t)BB * SS * HH * DD;

  // workspace layout (bytes); ws_size ~256 MiB per harness fill
  char* ws = (char*)d_ws;
  float*          o_ln    = (float*)(ws);                       // 2 MB
  unsigned short* o_lnb   = (unsigned short*)(ws + 2097152);    // 1 MB
  unsigned short* w1b     = (unsigned short*)(ws + 3145728);    // 2 MB
  unsigned short* w2b     = (unsigned short*)(ws + 5242880);    // 2 MB
  unsigned short* h1b     = (unsigned short*)(ws + 7340032);    // 4 MB
  float*          ypart   = (float*)(ws + 11534336);            // 8 MB (4 slices)
  unsigned short* v_wb    = (unsigned short*)(ws + 19922944);   // 512 KB
  unsigned short* xab     = (unsigned short*)(ws + 20447232);   // 1 MB
  float*          vpart   = (float*)(ws + 21495808);            // 8 MB (4 slices)
  float*          logits  = (float*)(ws + 29884416);            // 512 KB

  pre_kernel<<<NLOGIT_BLK + NCAST_BLK, 256, 0, stream>>>(
      x, mask, w, w1, w2, v_w, w1b, w2b, v_wb, logits);
  xa_kernel<<<BB * SS * 2, 512, 0, stream>>>(x, logits, attn, xab);
  gemm_v_kernel<<<512, 256, 0, stream>>>(xab, v_wb, vpart);
  ln_mid_kernel<<<256, 256, 0, stream>>>(vpart, ln_g, ln_b, o_ln, o_lnb);
  gemm1_kernel<<<512, 256, 0, stream>>>(o_lnb, w1b, b1, h1b);
  gemm2_kernel<<<512, 256, 0, stream>>>(h1b, w2b, ypart);
  ln_final_kernel<<<256, 256, 0, stream>>>(ypart, o_ln, b2, fln_g, fln_b, y);
}